// Round 4
// baseline (1329.244 us; speedup 1.0000x reference)
//
#include <hip/hip_runtime.h>
#include <stdint.h>

#define N_ROWS 200000
#define NIMG   500
#define DMETA  24
#define WIDTH  32
#define HID    64
#define DEPTH  20
#define MC     32

// ws layout (floats):
//   [0, 16000)        sums -> pooled (in-place normalize)
//   [16000, 56960)    w1t: transposed mlp_w1, w1t[l][j][k] = w1[l][k][j]
#define WS_SUMS  0
#define WS_W1T   16000

__device__ __forceinline__ uint32_t rotl32(uint32_t x, int r) {
    return (x << r) | (x >> (32 - r));
}

// JAX *partitionable* threefry bits for key (0,42), bit_width=32:
//   counts1, counts2 = iota_2x32_shape(shape)        # (hi, lo) words of u64 iota
//   bits1, bits2 = threefry2x32(key, (counts1, counts2))
//   out = bits1 ^ bits2                              # XOR-fold for 8/16/32-bit widths
// For our sizes hi = 0, lo = j. [jax_threefry_partitionable=True, JAX >= 0.4.36]
__device__ __forceinline__ uint32_t tf_bits(uint32_t j) {
    const uint32_t ks1 = 42u, ks2 = 0x1BD11BDAu ^ 42u;  // ks0 = 0
    uint32_t x0 = 0u;        // counts_hi (0) + ks0 (0)
    uint32_t x1 = j + ks1;   // counts_lo + ks1
#define R4(a,b,c,d) \
    x0 += x1; x1 = rotl32(x1,(a)); x1 ^= x0; \
    x0 += x1; x1 = rotl32(x1,(b)); x1 ^= x0; \
    x0 += x1; x1 = rotl32(x1,(c)); x1 ^= x0; \
    x0 += x1; x1 = rotl32(x1,(d)); x1 ^= x0;
    R4(13,15,26,6)  x0 += ks1; x1 += ks2 + 1u;
    R4(17,29,16,24) x0 += ks2; x1 += 0u + 2u;
    R4(13,15,26,6)  /* x0 += ks0 */ x1 += ks1 + 3u;
    R4(17,29,16,24) x0 += ks1; x1 += ks2 + 4u;
    R4(13,15,26,6)  x0 += ks2; x1 += 0u + 5u;
#undef R4
    return x0 ^ x1;
}

// JAX uniform(lo=nextafter(-1,0), hi=1) then sqrt(2)*erfinv.
// (hi-lo) rounds to exactly 2.0f in f32 (tie-to-even at the midpoint).
__device__ __forceinline__ float bits_to_normal(uint32_t b) {
    float f = __uint_as_float((b >> 9) | 0x3f800000u) - 1.0f;  // [0,1)
    const float lo = -0.99999994f;                              // nextafter(-1,0)
    float u = f * 2.0f + lo;
    u = fmaxf(lo, u);
    return 1.41421356f * erfinvf(u);
}

// 20 residual MLP blocks, weights via wave-uniform (scalar) loads.
__device__ __forceinline__ void mlp20(float h[WIDTH],
                                      const float* __restrict__ w1t,
                                      const float* __restrict__ b1,
                                      const float* __restrict__ w2,
                                      const float* __restrict__ b2) {
#pragma unroll 1
    for (int l = 0; l < DEPTH; ++l) {
        const float* W1 = w1t + l * (WIDTH * HID);   // [j][k]
        const float* B1 = b1 + l * HID;
        const float* W2 = w2 + l * (HID * WIDTH);    // [j][k]
        const float* B2 = b2 + l * WIDTH;
        float acc[WIDTH];
#pragma unroll
        for (int k = 0; k < WIDTH; ++k) acc[k] = B2[k];
#pragma unroll 4
        for (int j = 0; j < HID; ++j) {
            float a = B1[j];
#pragma unroll
            for (int k = 0; k < WIDTH; ++k) a = fmaf(h[k], W1[j * 32 + k], a);
            a = fmaxf(a, 0.0f);
#pragma unroll
            for (int k = 0; k < WIDTH; ++k) acc[k] = fmaf(a, W2[j * 32 + k], acc[k]);
        }
#pragma unroll
        for (int k = 0; k < WIDTH; ++k) h[k] += acc[k];
    }
}

// prep: zero pooled sums; transpose w1 into ws
__global__ __launch_bounds__(256) void prep_kernel(const float* __restrict__ w1,
                                                   float* __restrict__ ws) {
    int t = blockIdx.x * 256 + threadIdx.x;
    if (t < NIMG * WIDTH) ws[WS_SUMS + t] = 0.0f;
    if (t < DEPTH * WIDTH * HID) {
        int l = t >> 11;          // /2048
        int r = t & 2047;
        int k = r >> 6;           // /64
        int j = r & 63;
        ws[WS_W1T + l * 2048 + j * 32 + k] = w1[t];
    }
}

// pass A: h0 = [metadata, iobs, sigiobs] @ w_img + b; MLP; plain atomic segment-sum
__global__ __launch_bounds__(256) void pass_a(
    const float* __restrict__ md, const float* __restrict__ iobs,
    const float* __restrict__ sig, const float* __restrict__ wimg,
    const float* __restrict__ bimg, const float* __restrict__ w1t,
    const float* __restrict__ b1, const float* __restrict__ w2,
    const float* __restrict__ b2, const int* __restrict__ ids,
    float* __restrict__ sums) {
    int i = blockIdx.x * 256 + threadIdx.x;
    if (i >= N_ROWS) return;

    float x[26];
    const float4* m4 = reinterpret_cast<const float4*>(md + (size_t)i * DMETA);
#pragma unroll
    for (int q = 0; q < 6; ++q) {
        float4 v = m4[q];
        x[q * 4 + 0] = v.x; x[q * 4 + 1] = v.y; x[q * 4 + 2] = v.z; x[q * 4 + 3] = v.w;
    }
    x[24] = iobs[i];
    x[25] = sig[i];

    float h[WIDTH];
#pragma unroll
    for (int c = 0; c < WIDTH; ++c) h[c] = bimg[c];
#pragma unroll 2
    for (int d = 0; d < 26; ++d) {
#pragma unroll
        for (int c = 0; c < WIDTH; ++c) h[c] = fmaf(x[d], wimg[d * 32 + c], h[c]);
    }

    mlp20(h, w1t, b1, w2, b2);

    // literal per-row atomic segment-sum; channel order staggered by lane so a
    // wave's 64 lanes (mostly same image) hit 32 distinct addresses per step.
    int id = ids[i];
    int lane = threadIdx.x & 63;
#pragma unroll 1
    for (int cc = 0; cc < WIDTH; ++cc) {
        int c = (cc + lane) & 31;
        atomicAdd(&sums[id * 32 + c], h[c]);
    }
}

// normalize: pooled = sums / max(count,1), in-place
__global__ __launch_bounds__(256) void normalize_kernel(float* __restrict__ sums,
                                                        const int* __restrict__ cnts) {
    int t = blockIdx.x * 256 + threadIdx.x;
    if (t < NIMG * WIDTH) {
        int img = t >> 5;
        float c = (float)max(cnts[img], 1);
        sums[t] = sums[t] / c;
    }
}

// pass B: s0 = metadata @ w_scale + b + pooled[id]; MLP; head; sample; outputs
__global__ __launch_bounds__(256) void pass_b(
    const float* __restrict__ md, const float* __restrict__ wsc,
    const float* __restrict__ bsc, const float* __restrict__ w1t,
    const float* __restrict__ b1, const float* __restrict__ w2,
    const float* __restrict__ b2, const float* __restrict__ wout,
    const float* __restrict__ bout, const int* __restrict__ ids,
    const float* __restrict__ pooled, float* __restrict__ out) {
    int i = blockIdx.x * 256 + threadIdx.x;
    if (i >= N_ROWS) return;

    float x[24];
    const float4* m4 = reinterpret_cast<const float4*>(md + (size_t)i * DMETA);
#pragma unroll
    for (int q = 0; q < 6; ++q) {
        float4 v = m4[q];
        x[q * 4 + 0] = v.x; x[q * 4 + 1] = v.y; x[q * 4 + 2] = v.z; x[q * 4 + 3] = v.w;
    }
    int id = ids[i];

    float h[WIDTH];
#pragma unroll
    for (int c = 0; c < WIDTH; ++c) h[c] = bsc[c] + pooled[id * 32 + c];
#pragma unroll 2
    for (int d = 0; d < DMETA; ++d) {
#pragma unroll
        for (int c = 0; c < WIDTH; ++c) h[c] = fmaf(x[d], wsc[d * 32 + c], h[c]);
    }

    mlp20(h, w1t, b1, w2, b2);

    float p0 = bout[0], p1 = bout[1];
#pragma unroll
    for (int c = 0; c < WIDTH; ++c) {
        p0 = fmaf(h[c], wout[c * 2 + 0], p0);
        p1 = fmaf(h[c], wout[c * 2 + 1], p1);
    }
    float loc = p0;
    // softplus = logaddexp(x,0) = max(x,0) + log1p(exp(-|x|))
    float scale = fmaxf(p1, 0.0f) + log1pf(expf(-fabsf(p1))) + 1e-12f;
    float ls = logf(scale);

    float klsum = 0.0f;  // sum over samples of (-0.5*n^2 + |z|)
    float* zrow = out + (size_t)i * MC;
#pragma unroll 4
    for (int t = 0; t < 16; ++t) {
        uint32_t j0 = (uint32_t)(t * N_ROWS) + (uint32_t)i;   // flat idx, sample t
        uint32_t j1 = j0 + 3200000u;                          // sample t+16
        float n0 = bits_to_normal(tf_bits(j0));
        float n1 = bits_to_normal(tf_bits(j1));
        float z0 = fmaf(scale, n0, loc);
        float z1 = fmaf(scale, n1, loc);
        zrow[t] = z0;
        zrow[t + 16] = z1;
        klsum += fmaf(-0.5f, n0 * n0, fabsf(z0));
        klsum += fmaf(-0.5f, n1 * n1, fabsf(z1));
    }
    // kl = KLW * ( mean(-0.5 n^2 + |z|) - log(scale) - 0.5*log(2pi) + log(2) )
    float kl = 0.01f * (klsum * (1.0f / 32.0f) - ls - 0.91893853320467274f + 0.69314718055994531f);
    out[(size_t)N_ROWS * MC + i] = kl;
}

extern "C" void kernel_launch(void* const* d_in, const int* in_sizes, int n_in,
                              void* d_out, int out_size, void* d_ws, size_t ws_size,
                              hipStream_t stream) {
    const float* md   = (const float*)d_in[0];
    const float* iobs = (const float*)d_in[1];
    const float* sig  = (const float*)d_in[2];
    const float* wimg = (const float*)d_in[3];
    const float* bimg = (const float*)d_in[4];
    const float* wsc  = (const float*)d_in[5];
    const float* bsc  = (const float*)d_in[6];
    const float* w1   = (const float*)d_in[7];
    const float* b1   = (const float*)d_in[8];
    const float* w2   = (const float*)d_in[9];
    const float* b2   = (const float*)d_in[10];
    const float* wout = (const float*)d_in[11];
    const float* bout = (const float*)d_in[12];
    const int* ids    = (const int*)d_in[13];
    const int* cnts   = (const int*)d_in[14];
    float* out = (float*)d_out;
    float* ws  = (float*)d_ws;
    float* sums = ws + WS_SUMS;
    float* w1t  = ws + WS_W1T;

    const int nblk = (N_ROWS + 255) / 256;
    prep_kernel<<<(DEPTH * WIDTH * HID + 255) / 256, 256, 0, stream>>>(w1, ws);
    pass_a<<<nblk, 256, 0, stream>>>(md, iobs, sig, wimg, bimg, w1t, b1, w2, b2, ids, sums);
    normalize_kernel<<<(NIMG * WIDTH + 255) / 256, 256, 0, stream>>>(sums, cnts);
    pass_b<<<nblk, 256, 0, stream>>>(md, wsc, bsc, w1t, b1, w2, b2, wout, bout, ids, sums, out);
}